// Round 4
// baseline (510.371 us; speedup 1.0000x reference)
//
#include <hip/hip_runtime.h>
#include <hip/hip_bf16.h>

// Problem constants
constexpr int DIMD  = 1152;
constexpr int NHD   = 12;     // query heads
constexpr int KVHD  = 2;      // kv heads
constexpr int HDD   = 96;     // head dim
constexpr int GRPS  = 6;      // GQA group size
constexpr int SEQL  = 2048;
constexpr int BSZ4  = 4;
constexpr int MROWS = BSZ4 * SEQL;           // 8192
constexpr int NQKV  = DIMD + 2 * KVHD * HDD; // 1536
constexpr float SCALE = 0.10206207261596577f; // 96^-0.5

typedef short  bf16x8 __attribute__((ext_vector_type(8)));
typedef float  f32x4  __attribute__((ext_vector_type(4)));

typedef __attribute__((address_space(3))) unsigned int       lds_u32_t;
typedef __attribute__((address_space(1))) const unsigned int glb_u32_t;

__device__ __forceinline__ void gload16(const unsigned short* g, unsigned short* l) {
    // async global->LDS DMA, 16B/lane; LDS dest = wave-uniform base + lane*16
    __builtin_amdgcn_global_load_lds((glb_u32_t*)(const void*)g,
                                     (lds_u32_t*)(void*)l, 16, 0, 0);
}

__device__ __forceinline__ unsigned short f2bf(float f) {
    unsigned int u = __builtin_bit_cast(unsigned int, f);
    u += 0x7fff + ((u >> 16) & 1);   // RNE
    return (unsigned short)(u >> 16);
}

// ---------------------------------------------------------------------------
// fp32 -> bf16 elementwise convert
// ---------------------------------------------------------------------------
__global__ __launch_bounds__(256) void cvt_bf16_kernel(
    const float4* __restrict__ src, ushort4* __restrict__ dst, int n4)
{
    int i = blockIdx.x * 256 + threadIdx.x;
    if (i < n4) {
        float4 f = src[i];
        ushort4 o;
        o.x = f2bf(f.x); o.y = f2bf(f.y); o.z = f2bf(f.z); o.w = f2bf(f.w);
        dst[i] = o;
    }
}

// ---------------------------------------------------------------------------
// Kernel 1: QKV projection, bf16 MFMA (m97 structure) + bias + RoPE + scatter
// (unchanged from R3)
// ---------------------------------------------------------------------------
__global__ __launch_bounds__(256) void qkv_mfma_kernel(
    const unsigned short* __restrict__ xb,  const unsigned short* __restrict__ qwb,
    const unsigned short* __restrict__ kvwb,
    const float* __restrict__ qb,  const float* __restrict__ kvb,
    const int* __restrict__ start_pos,
    unsigned short* __restrict__ Qo, unsigned short* __restrict__ Ko,
    unsigned short* __restrict__ VTo)
{
    __shared__ __align__(16) unsigned short As[128 * 32];
    __shared__ __align__(16) unsigned short Bs[128 * 32];

    const int tid  = threadIdx.x;
    const int w    = tid >> 6;
    const int lane = tid & 63;
    const int l16  = lane & 15;
    const int quad = lane >> 4;
    const int wm   = w >> 1, wn = w & 1;
    const int m0   = blockIdx.y * 128;
    const int n0   = blockIdx.x * 128;

    const unsigned short* Abase = xb + (size_t)m0 * DIMD;
    const unsigned short* Bbase = (n0 < DIMD)
        ? qwb  + (size_t)n0 * DIMD
        : kvwb + (size_t)(n0 - DIMD) * DIMD;

    const int srow = w * 16 + (lane >> 2);
    const int scol = (lane & 3) * 8;

    f32x4 acc[4][4];
    #pragma unroll
    for (int mi = 0; mi < 4; mi++)
        #pragma unroll
        for (int ni = 0; ni < 4; ni++) acc[mi][ni] = (f32x4){0.f, 0.f, 0.f, 0.f};

    for (int k0 = 0; k0 < DIMD; k0 += 32) {
        gload16(Abase + (size_t)srow        * DIMD + k0 + scol, &As[w * 512]);
        gload16(Abase + (size_t)(srow + 64) * DIMD + k0 + scol, &As[2048 + w * 512]);
        gload16(Bbase + (size_t)srow        * DIMD + k0 + scol, &Bs[w * 512]);
        gload16(Bbase + (size_t)(srow + 64) * DIMD + k0 + scol, &Bs[2048 + w * 512]);
        __syncthreads();
        bf16x8 af[4], bfr[4];
        #pragma unroll
        for (int mi = 0; mi < 4; mi++)
            af[mi] = *(const bf16x8*)&As[(wm * 64 + mi * 16 + l16) * 32 + quad * 8];
        #pragma unroll
        for (int ni = 0; ni < 4; ni++)
            bfr[ni] = *(const bf16x8*)&Bs[(wn * 64 + ni * 16 + l16) * 32 + quad * 8];
        #pragma unroll
        for (int mi = 0; mi < 4; mi++)
            #pragma unroll
            for (int ni = 0; ni < 4; ni++)
                acc[mi][ni] = __builtin_amdgcn_mfma_f32_16x16x32_bf16(
                    af[mi], bfr[ni], acc[mi][ni], 0, 0, 0);
        __syncthreads();
    }

    const int sp = *start_pos;
    #pragma unroll
    for (int ni = 0; ni < 4; ni++) {
        const int n   = n0 + wn * 64 + ni * 16 + l16;
        const bool isQ = (n < DIMD);
        const int jj  = n - DIMD;
        const bool isK = !isQ && (jj < KVHD * HDD);
        const int d   = isQ ? (n % HDD) : (jj % HDD);
        const int hh  = isQ ? (n / HDD) : ((jj / HDD) & 1);
        const float bias = isQ ? qb[n] : kvb[jj];
        const bool doRope = isQ || isK;
        const int de = d & ~1;
        const float th = doRope ? powf(10000.0f, -(float)de / 96.0f) : 0.0f;
        const float sg = (n & 1) ? 1.0f : -1.0f;
        #pragma unroll
        for (int mi = 0; mi < 4; mi++) {
            #pragma unroll
            for (int r = 0; r < 4; r++) {
                const int m = m0 + wm * 64 + mi * 16 + quad * 4 + r;
                const int b = m >> 11;
                const int s = m & (SEQL - 1);
                float v  = acc[mi][ni][r] + bias;
                float pv = __shfl_xor(v, 1, 64);
                float o = v;
                if (doRope) {
                    float ang = (float)(s + sp) * th;
                    float sn, cs; sincosf(ang, &sn, &cs);
                    o = v * cs + sg * pv * sn;
                }
                if (isQ)
                    Qo[(((size_t)b * NHD + hh) * SEQL + s) * HDD + d] = f2bf(o);
                else if (isK)
                    Ko[(((size_t)b * KVHD + hh) * SEQL + s) * HDD + d] = f2bf(o);
                else
                    VTo[(((size_t)b * KVHD + hh) * HDD + d) * SEQL + s] = f2bf(o);
            }
        }
    }
}

// ---------------------------------------------------------------------------
// Kernel 2: bf16 MFMA causal flash attention, Round-4 rewrite.
//  - S^T = K*Q^T (swapped operands): lane-local softmax (1 q-row/lane),
//    2 shuffles per reduction, packed b64 P stores.
//  - 128 q-rows per WG (2 m-tiles/wave) amortize K/V fragment reads.
//  - Double-buffered global_load_lds staging (prefetch next k-block after
//    the single per-iteration barrier).
// LDS: Ks 2*64*104*2 + VTs 2*96*72*2 + Ps 4*16*72*2 = 63488 B -> 2 WG/CU.
// ---------------------------------------------------------------------------
__global__ __launch_bounds__(256) void attn_mfma_kernel(
    const unsigned short* __restrict__ Q, const unsigned short* __restrict__ K,
    const unsigned short* __restrict__ VT, unsigned short* __restrict__ AO)
{
    __shared__ __align__(16) unsigned short Ks[2][64 * 104];  // 13 16B-slots/row
    __shared__ __align__(16) unsigned short VTs[2][96 * 72];  // 9 16B-slots/row
    __shared__ __align__(16) unsigned short Ps[4][16 * 72];   // per-wave P buffer

    const int tid  = threadIdx.x;
    const int w    = tid >> 6;
    const int lane = tid & 63;
    const int l16  = lane & 15;
    const int quad = lane >> 4;
    const int qt   = (int)(gridDim.x - 1) - (int)blockIdx.x;  // heavy first
    const int h    = blockIdx.y;
    const int b    = blockIdx.z;
    const int kvh  = h / GRPS;
    const int nkb  = 2 * qt + 2;

    const unsigned short* Qbase  = Q  + (((size_t)b * NHD  + h)   * SEQL) * HDD;
    const unsigned short* Kbase  = K  + (((size_t)b * KVHD + kvh) * SEQL) * HDD;
    const unsigned short* VTbase = VT + (((size_t)b * KVHD + kvh) * HDD)  * SEQL;

    // --- staging slot precompute (slot = instr*64 + lane; padded-row mapping)
    int kof[4]; bool kOK[4]; int kds[4];
    int vof[4]; bool vOK[4]; int vds[4];
    #pragma unroll
    for (int j = 0; j < 4; j++) {
        const int i = w + 4 * j;
        kOK[j] = (i < 13);                  // 13 instrs cover 64*13 = 832 slots
        kds[j] = i * 512;
        kof[j] = 0;
        if (kOK[j]) {
            int slot = i * 64 + lane;
            int r = slot / 13, g = slot - r * 13;
            kof[j] = r * HDD + (g < 12 ? g * 8 : 0);   // g==12 is row pad
        }
        vOK[j] = (i < 13) || (i == 13 && lane < 32);   // 864 slots = 13.5 instrs
        vds[j] = i * 512;
        vof[j] = 0;
        if (i <= 13) {
            int slot = i * 64 + lane;
            if (slot < 864) {
                int r = slot / 9, g = slot - r * 9;
                vof[j] = r * SEQL + (g < 8 ? g * 8 : 0);  // g==8 is row pad
            }
        }
    }

    // --- Q fragments in registers (2 m-tiles x K=96)
    bf16x8 qf[2][3];
    #pragma unroll
    for (int mt = 0; mt < 2; mt++) {
        const int qrow = qt * 128 + mt * 64 + w * 16 + l16;
        const unsigned short* qp = Qbase + (size_t)qrow * HDD + quad * 8;
        qf[mt][0] = *(const bf16x8*)(qp);
        qf[mt][1] = *(const bf16x8*)(qp + 32);
        qf[mt][2] = *(const bf16x8*)(qp + 64);
    }

    float m_r[2] = {-1e30f, -1e30f};
    float l_r[2] = {0.0f, 0.0f};
    f32x4 oacc[2][6];
    #pragma unroll
    for (int mt = 0; mt < 2; mt++)
        #pragma unroll
        for (int nn = 0; nn < 6; nn++) oacc[mt][nn] = (f32x4){0.f, 0.f, 0.f, 0.f};

    // --- prefetch k-block 0 into buffer 0
    #pragma unroll
    for (int j = 0; j < 4; j++)
        if (kOK[j]) gload16(Kbase + kof[j], &Ks[0][kds[j]]);
    #pragma unroll
    for (int j = 0; j < 4; j++)
        if (vOK[j]) gload16(VTbase + vof[j], &VTs[0][vds[j]]);

    for (int kb = 0; kb < nkb; kb++) {
        const int k0  = kb * 64;
        const int buf = kb & 1;
        __syncthreads();   // drains the prefetch for this buffer + last iter's reads

        // prefetch next k-block into the other buffer (overlaps this compute)
        if (kb + 1 < nkb) {
            const unsigned short* ksrc = Kbase + (size_t)(k0 + 64) * HDD;
            const unsigned short* vsrc = VTbase + (k0 + 64);
            #pragma unroll
            for (int j = 0; j < 4; j++)
                if (kOK[j]) gload16(ksrc + kof[j], &Ks[buf ^ 1][kds[j]]);
            #pragma unroll
            for (int j = 0; j < 4; j++)
                if (vOK[j]) gload16(vsrc + vof[j], &VTs[buf ^ 1][vds[j]]);
        }

        const bool do0 = (kb <= 2 * qt);   // mt0 fully masked on the last k-block

        // ---- S^T = K * Q^T : C-layout col = q-row (l16), row = t (quad*4+r)
        f32x4 s0[4], s1[4];
        #pragma unroll
        for (int n = 0; n < 4; n++) {
            const unsigned short* kr = &Ks[buf][(n * 16 + l16) * 104 + quad * 8];
            bf16x8 kf0 = *(const bf16x8*)(kr);
            bf16x8 kf1 = *(const bf16x8*)(kr + 32);
            bf16x8 kf2 = *(const bf16x8*)(kr + 64);
            f32x4 a1 = (f32x4){0.f, 0.f, 0.f, 0.f};
            a1 = __builtin_amdgcn_mfma_f32_16x16x32_bf16(kf0, qf[1][0], a1, 0, 0, 0);
            a1 = __builtin_amdgcn_mfma_f32_16x16x32_bf16(kf1, qf[1][1], a1, 0, 0, 0);
            a1 = __builtin_amdgcn_mfma_f32_16x16x32_bf16(kf2, qf[1][2], a1, 0, 0, 0);
            s1[n] = a1;
            if (do0) {
                f32x4 a0 = (f32x4){0.f, 0.f, 0.f, 0.f};
                a0 = __builtin_amdgcn_mfma_f32_16x16x32_bf16(kf0, qf[0][0], a0, 0, 0, 0);
                a0 = __builtin_amdgcn_mfma_f32_16x16x32_bf16(kf1, qf[0][1], a0, 0, 0, 0);
                a0 = __builtin_amdgcn_mfma_f32_16x16x32_bf16(kf2, qf[0][2], a0, 0, 0, 0);
                s0[n] = a0;
            }
        }

        // ---- lane-local online softmax + packed P store (per m-tile)
        float albc0[4], albc1[4];
        auto softmax_mt = [&](f32x4* s, int mt, float* albc) {
            const int qabs = qt * 128 + mt * 64 + w * 16 + l16;
            float v[4][4];
            float mx = -3e30f;
            #pragma unroll
            for (int n = 0; n < 4; n++)
                #pragma unroll
                for (int r = 0; r < 4; r++) {
                    const int t = k0 + n * 16 + quad * 4 + r;
                    float x = s[n][r] * SCALE;
                    if (t > qabs) x = -1e30f;
                    v[n][r] = x;
                    mx = fmaxf(mx, x);
                }
            mx = fmaxf(mx, __shfl_xor(mx, 16, 64));
            mx = fmaxf(mx, __shfl_xor(mx, 32, 64));
            const float mnew = fmaxf(m_r[mt], mx);
            const float al = __expf(m_r[mt] - mnew);
            float sum = 0.0f;
            #pragma unroll
            for (int n = 0; n < 4; n++) {
                float p0 = __expf(v[n][0] - mnew);
                float p1 = __expf(v[n][1] - mnew);
                float p2 = __expf(v[n][2] - mnew);
                float p3 = __expf(v[n][3] - mnew);
                sum += (p0 + p1) + (p2 + p3);
                ushort4 pk;
                pk.x = f2bf(p0); pk.y = f2bf(p1); pk.z = f2bf(p2); pk.w = f2bf(p3);
                *(ushort4*)&Ps[w][l16 * 72 + n * 16 + quad * 4] = pk;   // b64, 2-way
            }
            sum += __shfl_xor(sum, 16, 64);
            sum += __shfl_xor(sum, 32, 64);
            l_r[mt] = l_r[mt] * al + sum;
            m_r[mt] = mnew;
            #pragma unroll
            for (int r = 0; r < 4; r++) albc[r] = __shfl(al, quad * 4 + r, 64);
        };

        bf16x8 pa0a, pa0b, pa1a, pa1b;
        if (do0) {
            softmax_mt(s0, 0, albc0);
            __builtin_amdgcn_wave_barrier();
            pa0a = *(const bf16x8*)&Ps[w][l16 * 72 + quad * 8];
            pa0b = *(const bf16x8*)&Ps[w][l16 * 72 + 32 + quad * 8];
            __builtin_amdgcn_wave_barrier();
        }
        softmax_mt(s1, 1, albc1);
        __builtin_amdgcn_wave_barrier();
        pa1a = *(const bf16x8*)&Ps[w][l16 * 72 + quad * 8];
        pa1b = *(const bf16x8*)&Ps[w][l16 * 72 + 32 + quad * 8];
        __builtin_amdgcn_wave_barrier();

        // ---- O = diag(alpha) O + P V   (V frags shared across m-tiles)
        #pragma unroll
        for (int nn = 0; nn < 6; nn++) {
            const unsigned short* vr = &VTs[buf][(nn * 16 + l16) * 72 + quad * 8];
            bf16x8 vb0 = *(const bf16x8*)(vr);
            bf16x8 vb1 = *(const bf16x8*)(vr + 32);
            if (do0) {
                f32x4 a = oacc[0][nn];
                #pragma unroll
                for (int r = 0; r < 4; r++) a[r] *= albc0[r];
                a = __builtin_amdgcn_mfma_f32_16x16x32_bf16(pa0a, vb0, a, 0, 0, 0);
                a = __builtin_amdgcn_mfma_f32_16x16x32_bf16(pa0b, vb1, a, 0, 0, 0);
                oacc[0][nn] = a;
            }
            f32x4 a = oacc[1][nn];
            #pragma unroll
            for (int r = 0; r < 4; r++) a[r] *= albc1[r];
            a = __builtin_amdgcn_mfma_f32_16x16x32_bf16(pa1a, vb0, a, 0, 0, 0);
            a = __builtin_amdgcn_mfma_f32_16x16x32_bf16(pa1b, vb1, a, 0, 0, 0);
            oacc[1][nn] = a;
        }
    }

    // ---- epilogue: normalize + bf16 store
    #pragma unroll
    for (int mt = 0; mt < 2; mt++) {
        const float linv = 1.0f / l_r[mt];
        float lb[4];
        #pragma unroll
        for (int r = 0; r < 4; r++) lb[r] = __shfl(linv, quad * 4 + r, 64);
        const int row0 = qt * 128 + mt * 64 + w * 16 + quad * 4;
        #pragma unroll
        for (int nn = 0; nn < 6; nn++) {
            #pragma unroll
            for (int r = 0; r < 4; r++) {
                AO[((size_t)b * SEQL + row0 + r) * DIMD + h * HDD + nn * 16 + l16] =
                    f2bf(oacc[mt][nn][r] * lb[r]);
            }
        }
    }
}

// ---------------------------------------------------------------------------
// Kernel 3: output projection, bf16 MFMA (unchanged from R3)
// ---------------------------------------------------------------------------
__global__ __launch_bounds__(256) void out_mfma_kernel(
    const unsigned short* __restrict__ Ab, const unsigned short* __restrict__ Wb,
    const float* __restrict__ wob, float* __restrict__ out)
{
    __shared__ __align__(16) unsigned short As[128 * 32];
    __shared__ __align__(16) unsigned short Bs[128 * 32];

    const int tid  = threadIdx.x;
    const int w    = tid >> 6;
    const int lane = tid & 63;
    const int l16  = lane & 15;
    const int quad = lane >> 4;
    const int wm   = w >> 1, wn = w & 1;
    const int m0   = blockIdx.y * 128;
    const int n0   = blockIdx.x * 128;

    const unsigned short* Abase = Ab + (size_t)m0 * DIMD;
    const unsigned short* Bbase = Wb + (size_t)n0 * DIMD;

    const int srow = w * 16 + (lane >> 2);
    const int scol = (lane & 3) * 8;

    f32x4 acc[4][4];
    #pragma unroll
    for (int mi = 0; mi < 4; mi++)
        #pragma unroll
        for (int ni = 0; ni < 4; ni++) acc[mi][ni] = (f32x4){0.f, 0.f, 0.f, 0.f};

    for (int k0 = 0; k0 < DIMD; k0 += 32) {
        gload16(Abase + (size_t)srow        * DIMD + k0 + scol, &As[w * 512]);
        gload16(Abase + (size_t)(srow + 64) * DIMD + k0 + scol, &As[2048 + w * 512]);
        gload16(Bbase + (size_t)srow        * DIMD + k0 + scol, &Bs[w * 512]);
        gload16(Bbase + (size_t)(srow + 64) * DIMD + k0 + scol, &Bs[2048 + w * 512]);
        __syncthreads();
        bf16x8 af[4], bfr[4];
        #pragma unroll
        for (int mi = 0; mi < 4; mi++)
            af[mi] = *(const bf16x8*)&As[(wm * 64 + mi * 16 + l16) * 32 + quad * 8];
        #pragma unroll
        for (int ni = 0; ni < 4; ni++)
            bfr[ni] = *(const bf16x8*)&Bs[(wn * 64 + ni * 16 + l16) * 32 + quad * 8];
        #pragma unroll
        for (int mi = 0; mi < 4; mi++)
            #pragma unroll
            for (int ni = 0; ni < 4; ni++)
                acc[mi][ni] = __builtin_amdgcn_mfma_f32_16x16x32_bf16(
                    af[mi], bfr[ni], acc[mi][ni], 0, 0, 0);
        __syncthreads();
    }

    #pragma unroll
    for (int ni = 0; ni < 4; ni++) {
        const int n = n0 + wn * 64 + ni * 16 + l16;
        const float bias = wob[n];
        #pragma unroll
        for (int mi = 0; mi < 4; mi++) {
            #pragma unroll
            for (int r = 0; r < 4; r++) {
                const int m = m0 + wm * 64 + mi * 16 + quad * 4 + r;
                out[(size_t)m * DIMD + n] = acc[mi][ni][r] + bias;
            }
        }
    }
}

// ---------------------------------------------------------------------------
extern "C" void kernel_launch(void* const* d_in, const int* in_sizes, int n_in,
                              void* d_out, int out_size, void* d_ws, size_t ws_size,
                              hipStream_t stream)
{
    const float* x   = (const float*)d_in[0];
    // d_in[1] = mask: exactly triu(-1e9, k=1) -> causal predicate in-kernel
    const float* qw  = (const float*)d_in[2];
    const float* qb  = (const float*)d_in[3];
    const float* kvw = (const float*)d_in[4];
    const float* kvb = (const float*)d_in[5];
    const float* wow = (const float*)d_in[6];
    const float* wob = (const float*)d_in[7];
    const int*   sp  = (const int*)d_in[8];

    const size_t xN   = (size_t)MROWS * DIMD;
    const size_t qwN  = (size_t)DIMD * DIMD;
    const size_t kvwN = (size_t)2 * KVHD * HDD * DIMD;
    const size_t qN   = (size_t)BSZ4 * NHD  * SEQL * HDD;
    const size_t kvN  = (size_t)BSZ4 * KVHD * SEQL * HDD;

    unsigned short* xb   = (unsigned short*)d_ws;
    unsigned short* qwb  = xb   + xN;
    unsigned short* kvwb = qwb  + qwN;
    unsigned short* wowb = kvwb + kvwN;
    unsigned short* Q16  = wowb + qwN;
    unsigned short* K16  = Q16  + qN;
    unsigned short* VT16 = K16  + kvN;
    unsigned short* AO16 = VT16 + kvN;

    cvt_bf16_kernel<<<(int)(xN / 4 + 255) / 256, 256, 0, stream>>>(
        (const float4*)x, (ushort4*)xb, (int)(xN / 4));
    cvt_bf16_kernel<<<(int)(qwN / 4 + 255) / 256, 256, 0, stream>>>(
        (const float4*)qw, (ushort4*)qwb, (int)(qwN / 4));
    cvt_bf16_kernel<<<(int)(kvwN / 4 + 255) / 256, 256, 0, stream>>>(
        (const float4*)kvw, (ushort4*)kvwb, (int)(kvwN / 4));
    cvt_bf16_kernel<<<(int)(qwN / 4 + 255) / 256, 256, 0, stream>>>(
        (const float4*)wow, (ushort4*)wowb, (int)(qwN / 4));

    qkv_mfma_kernel<<<dim3(NQKV / 128, MROWS / 128, 1), 256, 0, stream>>>(
        xb, qwb, kvwb, qb, kvb, sp, Q16, K16, VT16);
    attn_mfma_kernel<<<dim3(SEQL / 128, NHD, BSZ4), 256, 0, stream>>>(
        Q16, K16, VT16, AO16);
    out_mfma_kernel<<<dim3(DIMD / 128, MROWS / 128, 1), 256, 0, stream>>>(
        AO16, wowb, wob, (float*)d_out);
}

// Round 5
// 397.295 us; speedup vs baseline: 1.2846x; 1.2846x over previous
//
#include <hip/hip_runtime.h>
#include <hip/hip_bf16.h>

// Problem constants
constexpr int DIMD  = 1152;
constexpr int NHD   = 12;     // query heads
constexpr int KVHD  = 2;      // kv heads
constexpr int HDD   = 96;     // head dim
constexpr int GRPS  = 6;      // GQA group size
constexpr int SEQL  = 2048;
constexpr int BSZ4  = 4;
constexpr int MROWS = BSZ4 * SEQL;           // 8192
constexpr int NQKV  = DIMD + 2 * KVHD * HDD; // 1536
constexpr float SCALE = 0.10206207261596577f; // 96^-0.5

typedef short  bf16x8 __attribute__((ext_vector_type(8)));
typedef float  f32x4  __attribute__((ext_vector_type(4)));

typedef __attribute__((address_space(3))) unsigned int       lds_u32_t;
typedef __attribute__((address_space(1))) const unsigned int glb_u32_t;

__device__ __forceinline__ void gload16(const unsigned short* g, unsigned short* l) {
    // async global->LDS DMA, 16B/lane; LDS dest = wave-uniform base + lane*16
    __builtin_amdgcn_global_load_lds((glb_u32_t*)(const void*)g,
                                     (lds_u32_t*)(void*)l, 16, 0, 0);
}

__device__ __forceinline__ unsigned short f2bf(float f) {
    unsigned int u = __builtin_bit_cast(unsigned int, f);
    u += 0x7fff + ((u >> 16) & 1);   // RNE
    return (unsigned short)(u >> 16);
}

// ---------------------------------------------------------------------------
// fp32 -> bf16 elementwise convert
// ---------------------------------------------------------------------------
__global__ __launch_bounds__(256) void cvt_bf16_kernel(
    const float4* __restrict__ src, ushort4* __restrict__ dst, int n4)
{
    int i = blockIdx.x * 256 + threadIdx.x;
    if (i < n4) {
        float4 f = src[i];
        ushort4 o;
        o.x = f2bf(f.x); o.y = f2bf(f.y); o.z = f2bf(f.z); o.w = f2bf(f.w);
        dst[i] = o;
    }
}

// ---------------------------------------------------------------------------
// Kernel 1: QKV projection, bf16 MFMA (m97 structure) + bias + RoPE + scatter
// (unchanged from R3/R4)
// ---------------------------------------------------------------------------
__global__ __launch_bounds__(256) void qkv_mfma_kernel(
    const unsigned short* __restrict__ xb,  const unsigned short* __restrict__ qwb,
    const unsigned short* __restrict__ kvwb,
    const float* __restrict__ qb,  const float* __restrict__ kvb,
    const int* __restrict__ start_pos,
    unsigned short* __restrict__ Qo, unsigned short* __restrict__ Ko,
    unsigned short* __restrict__ VTo)
{
    __shared__ __align__(16) unsigned short As[128 * 32];
    __shared__ __align__(16) unsigned short Bs[128 * 32];

    const int tid  = threadIdx.x;
    const int w    = tid >> 6;
    const int lane = tid & 63;
    const int l16  = lane & 15;
    const int quad = lane >> 4;
    const int wm   = w >> 1, wn = w & 1;
    const int m0   = blockIdx.y * 128;
    const int n0   = blockIdx.x * 128;

    const unsigned short* Abase = xb + (size_t)m0 * DIMD;
    const unsigned short* Bbase = (n0 < DIMD)
        ? qwb  + (size_t)n0 * DIMD
        : kvwb + (size_t)(n0 - DIMD) * DIMD;

    const int srow = w * 16 + (lane >> 2);
    const int scol = (lane & 3) * 8;

    f32x4 acc[4][4];
    #pragma unroll
    for (int mi = 0; mi < 4; mi++)
        #pragma unroll
        for (int ni = 0; ni < 4; ni++) acc[mi][ni] = (f32x4){0.f, 0.f, 0.f, 0.f};

    for (int k0 = 0; k0 < DIMD; k0 += 32) {
        gload16(Abase + (size_t)srow        * DIMD + k0 + scol, &As[w * 512]);
        gload16(Abase + (size_t)(srow + 64) * DIMD + k0 + scol, &As[2048 + w * 512]);
        gload16(Bbase + (size_t)srow        * DIMD + k0 + scol, &Bs[w * 512]);
        gload16(Bbase + (size_t)(srow + 64) * DIMD + k0 + scol, &Bs[2048 + w * 512]);
        __syncthreads();
        bf16x8 af[4], bfr[4];
        #pragma unroll
        for (int mi = 0; mi < 4; mi++)
            af[mi] = *(const bf16x8*)&As[(wm * 64 + mi * 16 + l16) * 32 + quad * 8];
        #pragma unroll
        for (int ni = 0; ni < 4; ni++)
            bfr[ni] = *(const bf16x8*)&Bs[(wn * 64 + ni * 16 + l16) * 32 + quad * 8];
        #pragma unroll
        for (int mi = 0; mi < 4; mi++)
            #pragma unroll
            for (int ni = 0; ni < 4; ni++)
                acc[mi][ni] = __builtin_amdgcn_mfma_f32_16x16x32_bf16(
                    af[mi], bfr[ni], acc[mi][ni], 0, 0, 0);
        __syncthreads();
    }

    const int sp = *start_pos;
    #pragma unroll
    for (int ni = 0; ni < 4; ni++) {
        const int n   = n0 + wn * 64 + ni * 16 + l16;
        const bool isQ = (n < DIMD);
        const int jj  = n - DIMD;
        const bool isK = !isQ && (jj < KVHD * HDD);
        const int d   = isQ ? (n % HDD) : (jj % HDD);
        const int hh  = isQ ? (n / HDD) : ((jj / HDD) & 1);
        const float bias = isQ ? qb[n] : kvb[jj];
        const bool doRope = isQ || isK;
        const int de = d & ~1;
        const float th = doRope ? powf(10000.0f, -(float)de / 96.0f) : 0.0f;
        const float sg = (n & 1) ? 1.0f : -1.0f;
        #pragma unroll
        for (int mi = 0; mi < 4; mi++) {
            #pragma unroll
            for (int r = 0; r < 4; r++) {
                const int m = m0 + wm * 64 + mi * 16 + quad * 4 + r;
                const int b = m >> 11;
                const int s = m & (SEQL - 1);
                float v  = acc[mi][ni][r] + bias;
                float pv = __shfl_xor(v, 1, 64);
                float o = v;
                if (doRope) {
                    float ang = (float)(s + sp) * th;
                    float sn, cs; sincosf(ang, &sn, &cs);
                    o = v * cs + sg * pv * sn;
                }
                if (isQ)
                    Qo[(((size_t)b * NHD + hh) * SEQL + s) * HDD + d] = f2bf(o);
                else if (isK)
                    Ko[(((size_t)b * KVHD + hh) * SEQL + s) * HDD + d] = f2bf(o);
                else
                    VTo[(((size_t)b * KVHD + hh) * HDD + d) * SEQL + s] = f2bf(o);
            }
        }
    }
}

// ---------------------------------------------------------------------------
// Kernel 2: bf16 MFMA causal flash attention, Round 5.
//  - 64 q-rows/WG (grid 1536 blocks, heavy-first) for load balance.
//  - Single-buffered K/V LDS staging via global_load_lds: 36.6 KB -> 4 WG/CU
//    (16 waves/CU); latency hidden by TLP, not explicit dbuf (R4 lesson).
//  - S^T = K*Q^T: lane-local softmax (q = l16), 2 shfl_xor per reduction.
//  - alpha / 1/l broadcast via LDS b128 (replaces 4 serial bpermutes).
// ---------------------------------------------------------------------------
__global__ __launch_bounds__(256, 4) void attn_mfma_kernel(
    const unsigned short* __restrict__ Q, const unsigned short* __restrict__ K,
    const unsigned short* __restrict__ VT, unsigned short* __restrict__ AO)
{
    __shared__ __align__(16) unsigned short Ks[64 * 104];   // 13 16B-slots/row
    __shared__ __align__(16) unsigned short VTs[96 * 72];   // 9 16B-slots/row
    __shared__ __align__(16) unsigned short Ps[4][16 * 72]; // per-wave P buffer
    __shared__ float Al[4][16];                             // per-wave bcast

    const int tid  = threadIdx.x;
    const int w    = tid >> 6;
    const int lane = tid & 63;
    const int l16  = lane & 15;
    const int quad = lane >> 4;
    const int qt   = (int)(gridDim.x - 1) - (int)blockIdx.x;  // heavy first
    const int h    = blockIdx.y;
    const int b    = blockIdx.z;
    const int kvh  = h / GRPS;
    const int nkb  = qt + 1;

    const unsigned short* Qbase  = Q  + (((size_t)b * NHD  + h)   * SEQL) * HDD;
    const unsigned short* Kbase  = K  + (((size_t)b * KVHD + kvh) * SEQL) * HDD;
    const unsigned short* VTbase = VT + (((size_t)b * KVHD + kvh) * HDD)  * SEQL;

    // --- staging maps: 27 gload16 slots/WG, instr i = w + 4*j (j = 0..6)
    //     i in [0,13): K tile rows (13 slots/row, slot 12 = pad-dup)
    //     i in [13,27): V^T tile rows (9 slots/row, slot 8 = pad-dup)
    int goff[7]; int gkind[7]; unsigned short* gdst[7];
    #pragma unroll
    for (int j = 0; j < 7; j++) {
        const int i = w + 4 * j;
        gkind[j] = 2; goff[j] = 0; gdst[j] = nullptr;
        if (i < 13) {
            int slot = i * 64 + lane;
            int r = slot / 13, g = slot - r * 13;
            goff[j]  = r * HDD + (g < 12 ? g * 8 : 0);
            gkind[j] = 0;
            gdst[j]  = &Ks[i * 512];
        } else if (i < 27) {
            int iv = i - 13;
            int slot = iv * 64 + lane;
            if (slot < 864) {
                int r = slot / 9, g = slot - r * 9;
                goff[j]  = r * SEQL + (g < 8 ? g * 8 : 0);
                gkind[j] = 1;
                gdst[j]  = &VTs[iv * 512];
            }
        }
    }

    // --- Q fragments in registers (A-layout: m = l16, k = quad*8 + j + 32*c)
    bf16x8 qf[3];
    {
        const int qrow = qt * 64 + w * 16 + l16;
        const unsigned short* qp = Qbase + (size_t)qrow * HDD + quad * 8;
        qf[0] = *(const bf16x8*)(qp);
        qf[1] = *(const bf16x8*)(qp + 32);
        qf[2] = *(const bf16x8*)(qp + 64);
    }

    float m_r = -1e30f, l_r = 0.0f;
    f32x4 oacc[6];
    #pragma unroll
    for (int nn = 0; nn < 6; nn++) oacc[nn] = (f32x4){0.f, 0.f, 0.f, 0.f};

    for (int kb = 0; kb < nkb; kb++) {
        const int k0 = kb * 64;
        // ---- stage K (64x96) + V^T (96x64) via async DMA
        #pragma unroll
        for (int j = 0; j < 7; j++) {
            if (gkind[j] == 0)
                gload16(Kbase + (size_t)k0 * HDD + goff[j], gdst[j]);
            else if (gkind[j] == 1) {
                if ((w + 4 * j) < 26 || lane < 32)
                    gload16(VTbase + k0 + goff[j], gdst[j]);
            }
        }
        __syncthreads();   // drains each wave's vmcnt -> tiles visible

        // ---- S^T = K * Q^T : C col (l16) = q-row, C row (quad*4+r) = t
        f32x4 s[4];
        #pragma unroll
        for (int n = 0; n < 4; n++) {
            const unsigned short* kr = &Ks[(n * 16 + l16) * 104 + quad * 8];
            bf16x8 kf0 = *(const bf16x8*)(kr);
            bf16x8 kf1 = *(const bf16x8*)(kr + 32);
            bf16x8 kf2 = *(const bf16x8*)(kr + 64);
            f32x4 a = (f32x4){0.f, 0.f, 0.f, 0.f};
            a = __builtin_amdgcn_mfma_f32_16x16x32_bf16(kf0, qf[0], a, 0, 0, 0);
            a = __builtin_amdgcn_mfma_f32_16x16x32_bf16(kf1, qf[1], a, 0, 0, 0);
            a = __builtin_amdgcn_mfma_f32_16x16x32_bf16(kf2, qf[2], a, 0, 0, 0);
            s[n] = a;
        }

        // ---- lane-local online softmax (q = l16)
        const int qabs = qt * 64 + w * 16 + l16;
        float v[4][4];
        float mx = -3e30f;
        #pragma unroll
        for (int n = 0; n < 4; n++)
            #pragma unroll
            for (int r = 0; r < 4; r++) {
                const int t = k0 + n * 16 + quad * 4 + r;
                float x = s[n][r] * SCALE;
                if (t > qabs) x = -1e30f;
                v[n][r] = x;
                mx = fmaxf(mx, x);
            }
        mx = fmaxf(mx, __shfl_xor(mx, 16, 64));
        mx = fmaxf(mx, __shfl_xor(mx, 32, 64));
        const float mnew = fmaxf(m_r, mx);
        const float al = __expf(m_r - mnew);
        float sum = 0.0f;
        #pragma unroll
        for (int n = 0; n < 4; n++) {
            float p0 = __expf(v[n][0] - mnew);
            float p1 = __expf(v[n][1] - mnew);
            float p2 = __expf(v[n][2] - mnew);
            float p3 = __expf(v[n][3] - mnew);
            sum += (p0 + p1) + (p2 + p3);
            ushort4 pk;
            pk.x = f2bf(p0); pk.y = f2bf(p1); pk.z = f2bf(p2); pk.w = f2bf(p3);
            *(ushort4*)&Ps[w][l16 * 72 + n * 16 + quad * 4] = pk;   // b64
        }
        sum += __shfl_xor(sum, 16, 64);
        sum += __shfl_xor(sum, 32, 64);
        l_r = l_r * al + sum;
        m_r = mnew;
        if (quad == 0) Al[w][l16] = al;   // q -> row broadcast via LDS
        __builtin_amdgcn_wave_barrier();

        const float4 alb = *(const float4*)&Al[w][quad * 4];
        bf16x8 pa0 = *(const bf16x8*)&Ps[w][l16 * 72 + quad * 8];
        bf16x8 pa1 = *(const bf16x8*)&Ps[w][l16 * 72 + 32 + quad * 8];
        const float albr[4] = {alb.x, alb.y, alb.z, alb.w};

        // ---- O = diag(alpha) O + P V  (O: col l16 = d, row quad*4+r = q)
        #pragma unroll
        for (int nn = 0; nn < 6; nn++) {
            const unsigned short* vr = &VTs[(nn * 16 + l16) * 72 + quad * 8];
            bf16x8 vb0 = *(const bf16x8*)(vr);
            bf16x8 vb1 = *(const bf16x8*)(vr + 32);
            f32x4 a = oacc[nn];
            #pragma unroll
            for (int r = 0; r < 4; r++) a[r] *= albr[r];
            a = __builtin_amdgcn_mfma_f32_16x16x32_bf16(pa0, vb0, a, 0, 0, 0);
            a = __builtin_amdgcn_mfma_f32_16x16x32_bf16(pa1, vb1, a, 0, 0, 0);
            oacc[nn] = a;
        }
        __syncthreads();   // all frag reads done before next stage overwrites
    }

    // ---- epilogue: normalize + bf16 store
    const float linv = 1.0f / l_r;
    if (quad == 0) Al[w][l16] = linv;
    __builtin_amdgcn_wave_barrier();
    const float4 lb4 = *(const float4*)&Al[w][quad * 4];
    const float lbr[4] = {lb4.x, lb4.y, lb4.z, lb4.w};
    const int row0 = qt * 64 + w * 16 + quad * 4;
    #pragma unroll
    for (int nn = 0; nn < 6; nn++) {
        #pragma unroll
        for (int r = 0; r < 4; r++) {
            AO[((size_t)b * SEQL + row0 + r) * DIMD + h * HDD + nn * 16 + l16] =
                f2bf(oacc[nn][r] * lbr[r]);
        }
    }
}

// ---------------------------------------------------------------------------
// Kernel 3: output projection, bf16 MFMA (unchanged from R3/R4)
// ---------------------------------------------------------------------------
__global__ __launch_bounds__(256) void out_mfma_kernel(
    const unsigned short* __restrict__ Ab, const unsigned short* __restrict__ Wb,
    const float* __restrict__ wob, float* __restrict__ out)
{
    __shared__ __align__(16) unsigned short As[128 * 32];
    __shared__ __align__(16) unsigned short Bs[128 * 32];

    const int tid  = threadIdx.x;
    const int w    = tid >> 6;
    const int lane = tid & 63;
    const int l16  = lane & 15;
    const int quad = lane >> 4;
    const int wm   = w >> 1, wn = w & 1;
    const int m0   = blockIdx.y * 128;
    const int n0   = blockIdx.x * 128;

    const unsigned short* Abase = Ab + (size_t)m0 * DIMD;
    const unsigned short* Bbase = Wb + (size_t)n0 * DIMD;

    const int srow = w * 16 + (lane >> 2);
    const int scol = (lane & 3) * 8;

    f32x4 acc[4][4];
    #pragma unroll
    for (int mi = 0; mi < 4; mi++)
        #pragma unroll
        for (int ni = 0; ni < 4; ni++) acc[mi][ni] = (f32x4){0.f, 0.f, 0.f, 0.f};

    for (int k0 = 0; k0 < DIMD; k0 += 32) {
        gload16(Abase + (size_t)srow        * DIMD + k0 + scol, &As[w * 512]);
        gload16(Abase + (size_t)(srow + 64) * DIMD + k0 + scol, &As[2048 + w * 512]);
        gload16(Bbase + (size_t)srow        * DIMD + k0 + scol, &Bs[w * 512]);
        gload16(Bbase + (size_t)(srow + 64) * DIMD + k0 + scol, &Bs[2048 + w * 512]);
        __syncthreads();
        bf16x8 af[4], bfr[4];
        #pragma unroll
        for (int mi = 0; mi < 4; mi++)
            af[mi] = *(const bf16x8*)&As[(wm * 64 + mi * 16 + l16) * 32 + quad * 8];
        #pragma unroll
        for (int ni = 0; ni < 4; ni++)
            bfr[ni] = *(const bf16x8*)&Bs[(wn * 64 + ni * 16 + l16) * 32 + quad * 8];
        #pragma unroll
        for (int mi = 0; mi < 4; mi++)
            #pragma unroll
            for (int ni = 0; ni < 4; ni++)
                acc[mi][ni] = __builtin_amdgcn_mfma_f32_16x16x32_bf16(
                    af[mi], bfr[ni], acc[mi][ni], 0, 0, 0);
        __syncthreads();
    }

    #pragma unroll
    for (int ni = 0; ni < 4; ni++) {
        const int n = n0 + wn * 64 + ni * 16 + l16;
        const float bias = wob[n];
        #pragma unroll
        for (int mi = 0; mi < 4; mi++) {
            #pragma unroll
            for (int r = 0; r < 4; r++) {
                const int m = m0 + wm * 64 + mi * 16 + quad * 4 + r;
                out[(size_t)m * DIMD + n] = acc[mi][ni][r] + bias;
            }
        }
    }
}

// ---------------------------------------------------------------------------
extern "C" void kernel_launch(void* const* d_in, const int* in_sizes, int n_in,
                              void* d_out, int out_size, void* d_ws, size_t ws_size,
                              hipStream_t stream)
{
    const float* x   = (const float*)d_in[0];
    // d_in[1] = mask: exactly triu(-1e9, k=1) -> causal predicate in-kernel
    const float* qw  = (const float*)d_in[2];
    const float* qb  = (const float*)d_in[3];
    const float* kvw = (const float*)d_in[4];
    const float* kvb = (const float*)d_in[5];
    const float* wow = (const float*)d_in[6];
    const float* wob = (const float*)d_in[7];
    const int*   sp  = (const int*)d_in[8];

    const size_t xN   = (size_t)MROWS * DIMD;
    const size_t qwN  = (size_t)DIMD * DIMD;
    const size_t kvwN = (size_t)2 * KVHD * HDD * DIMD;
    const size_t qN   = (size_t)BSZ4 * NHD  * SEQL * HDD;
    const size_t kvN  = (size_t)BSZ4 * KVHD * SEQL * HDD;

    unsigned short* xb   = (unsigned short*)d_ws;
    unsigned short* qwb  = xb   + xN;
    unsigned short* kvwb = qwb  + qwN;
    unsigned short* wowb = kvwb + kvwN;
    unsigned short* Q16  = wowb + qwN;
    unsigned short* K16  = Q16  + qN;
    unsigned short* VT16 = K16  + kvN;
    unsigned short* AO16 = VT16 + kvN;

    cvt_bf16_kernel<<<(int)(xN / 4 + 255) / 256, 256, 0, stream>>>(
        (const float4*)x, (ushort4*)xb, (int)(xN / 4));
    cvt_bf16_kernel<<<(int)(qwN / 4 + 255) / 256, 256, 0, stream>>>(
        (const float4*)qw, (ushort4*)qwb, (int)(qwN / 4));
    cvt_bf16_kernel<<<(int)(kvwN / 4 + 255) / 256, 256, 0, stream>>>(
        (const float4*)kvw, (ushort4*)kvwb, (int)(kvwN / 4));
    cvt_bf16_kernel<<<(int)(qwN / 4 + 255) / 256, 256, 0, stream>>>(
        (const float4*)wow, (ushort4*)wowb, (int)(qwN / 4));

    qkv_mfma_kernel<<<dim3(NQKV / 128, MROWS / 128, 1), 256, 0, stream>>>(
        xb, qwb, kvwb, qb, kvb, sp, Q16, K16, VT16);
    attn_mfma_kernel<<<dim3(SEQL / 64, NHD, BSZ4), 256, 0, stream>>>(
        Q16, K16, VT16, AO16);
    out_mfma_kernel<<<dim3(DIMD / 128, MROWS / 128, 1), 256, 0, stream>>>(
        AO16, wowb, wob, (float*)d_out);
}